// Round 1
// baseline (472.780 us; speedup 1.0000x reference)
//
#include <hip/hip_runtime.h>
#include <hip/hip_bf16.h>

#define D_MODEL 1024
#define BATCH 8
#define SEQ 4096
#define MROWS (BATCH*SEQ)   // 32768
#define NC 64               // number of scan chunks
#define CL 64               // chunk length (NC*CL == SEQ)

typedef __attribute__((ext_vector_type(4))) float f32x4;
typedef __attribute__((ext_vector_type(8))) short s16x8;

__device__ __forceinline__ unsigned short f2bf(float f){
  union { float f; unsigned int u; } v; v.f = f;
  return (unsigned short)((v.u + 0x7fffu + ((v.u >> 16) & 1u)) >> 16);
}
__device__ __forceinline__ float bf2f(unsigned int bits){
  union { unsigned int u; float f; } v; v.u = bits << 16; return v.f;
}

__device__ __forceinline__ void gload16(const void* g, void* l){
  __builtin_amdgcn_global_load_lds(
      (const __attribute__((address_space(1))) unsigned int*)g,
      (__attribute__((address_space(3))) unsigned int*)l, 16, 0, 0);
}

// ---------------- prep: x -> bf16 ----------------
__global__ __launch_bounds__(256)
void prep_x_kernel(const float* __restrict__ x, unsigned short* __restrict__ xb, int n4){
  int i = blockIdx.x*256 + threadIdx.x;
  int stride = gridDim.x*256;
  for (; i < n4; i += stride){
    float4 v = ((const float4*)x)[i];
    ushort4 o;
    o.x = f2bf(v.x); o.y = f2bf(v.y); o.z = f2bf(v.z); o.w = f2bf(v.w);
    ((ushort4*)xb)[i] = o;
  }
}

// ---------------- prep: weights -> bf16, decay ----------------
__global__ __launch_bounds__(256)
void prep_w_kernel(const float* __restrict__ Wi, const float* __restrict__ Wg,
                   const float* __restrict__ Wo, const float* __restrict__ ld,
                   unsigned short* __restrict__ Wib, unsigned short* __restrict__ Wgb,
                   unsigned short* __restrict__ Wob, float* __restrict__ decay){
  int i = blockIdx.x*256 + threadIdx.x;   // grid covers D*D/4 exactly
  {
    float4 a = ((const float4*)Wi)[i]; ushort4 o;
    o.x=f2bf(a.x); o.y=f2bf(a.y); o.z=f2bf(a.z); o.w=f2bf(a.w); ((ushort4*)Wib)[i]=o;
    a = ((const float4*)Wg)[i];
    o.x=f2bf(a.x); o.y=f2bf(a.y); o.z=f2bf(a.z); o.w=f2bf(a.w); ((ushort4*)Wgb)[i]=o;
    a = ((const float4*)Wo)[i];
    o.x=f2bf(a.x); o.y=f2bf(a.y); o.z=f2bf(a.z); o.w=f2bf(a.w); ((ushort4*)Wob)[i]=o;
  }
  if (i < D_MODEL){
    float v = ld[i];
    float sp = fmaxf(v, 0.f) + log1pf(expf(-fabsf(v)));   // stable softplus
    decay[i] = sp + 1e-4f;
  }
}

// ---------------- dual GEMM: update & gate, fused lambda/drive epilogue ----------------
// C[m][e] = sum_d X[m][d] * W[e][d]  (B^T layout: W rows are output cols)
__global__ __launch_bounds__(256, 2)
void gemm_dual_kernel(const unsigned short* __restrict__ Xb,
                      const unsigned short* __restrict__ Wib,
                      const unsigned short* __restrict__ Wgb,
                      const float* __restrict__ b_in,
                      const float* __restrict__ b_gate,
                      const float* __restrict__ decay,
                      const float* __restrict__ delta,
                      unsigned int* __restrict__ pack)
{
  __shared__ unsigned short sA[128*64];
  __shared__ unsigned short sBi[128*64];
  __shared__ unsigned short sBg[128*64];
  const int tid  = threadIdx.x;
  const int lane = tid & 63;
  const int wave = tid >> 6;
  const int wr = wave >> 1, wc = wave & 1;
  const int brow = blockIdx.y * 128;
  const int bcol = blockIdx.x * 128;

  const f32x4 zero = {0.f,0.f,0.f,0.f};
  f32x4 accU[4][4], accG[4][4];
  #pragma unroll
  for (int a=0;a<4;a++)
    #pragma unroll
    for (int b=0;b<4;b++){ accU[a][b]=zero; accG[a][b]=zero; }

  for (int kt = 0; kt < D_MODEL/64; ++kt){
    __syncthreads();
    const size_t kbyte = (size_t)kt*128;   // 64 bf16 = 128 bytes
    #pragma unroll
    for (int i=0;i<4;i++){
      const int ob = i*256 + wave*64;          // wave-uniform 16B-unit base
      const int o  = ob + lane;
      const int r  = o >> 3;                   // 8 x 16B per 128B row
      const int cb = (o & 7) * 16;
      gload16((const char*)Xb  + (size_t)(brow + r)*(D_MODEL*2) + kbyte + cb, (char*)sA  + (size_t)ob*16);
      gload16((const char*)Wib + (size_t)(bcol + r)*(D_MODEL*2) + kbyte + cb, (char*)sBi + (size_t)ob*16);
      gload16((const char*)Wgb + (size_t)(bcol + r)*(D_MODEL*2) + kbyte + cb, (char*)sBg + (size_t)ob*16);
    }
    __syncthreads();   // compiler drains vmcnt before s_barrier
    #pragma unroll
    for (int ks=0; ks<2; ++ks){
      s16x8 af[4], bi[4], bg[4];
      #pragma unroll
      for (int mi=0; mi<4; mi++){
        int row = wr*64 + mi*16 + (lane & 15);
        int boff = row*128 + ks*64 + ((lane>>4)*16);
        af[mi] = *(const s16x8*)((const char*)sA + boff);
      }
      #pragma unroll
      for (int ni=0; ni<4; ni++){
        int n = wc*64 + ni*16 + (lane & 15);
        int boff = n*128 + ks*64 + ((lane>>4)*16);
        bi[ni] = *(const s16x8*)((const char*)sBi + boff);
        bg[ni] = *(const s16x8*)((const char*)sBg + boff);
      }
      #pragma unroll
      for (int mi=0; mi<4; mi++)
        #pragma unroll
        for (int ni=0; ni<4; ni++){
          accU[mi][ni] = __builtin_amdgcn_mfma_f32_16x16x32_bf16(af[mi], bi[ni], accU[mi][ni], 0,0,0);
          accG[mi][ni] = __builtin_amdgcn_mfma_f32_16x16x32_bf16(af[mi], bg[ni], accG[mi][ni], 0,0,0);
        }
    }
  }
  // epilogue: u,g -> lambda/drive, packed bf16x2 {drive(hi), 1-lambda(lo)}
  #pragma unroll
  for (int ni=0; ni<4; ni++){
    const int col = bcol + wc*64 + ni*16 + (lane & 15);
    const float vb = b_in[col], vg = b_gate[col], dc = decay[col];
    #pragma unroll
    for (int mi=0; mi<4; mi++){
      #pragma unroll
      for (int q=0; q<4; q++){
        const int row = brow + wr*64 + mi*16 + ((lane>>4)*4) + q;
        const size_t idx = (size_t)row*D_MODEL + col;
        float u = accU[mi][ni][q] + vb;
        float z = accG[mi][ni][q] + vg;
        float g = 1.f/(1.f + __expf(-z));
        float dt = fmaxf(delta[idx], 1e-4f);
        float lam = __expf(-dc*dt);
        float omla = 1.f - lam;
        float drv = omla * g * u;
        pack[idx] = ((unsigned int)f2bf(drv) << 16) | (unsigned int)f2bf(omla);
      }
    }
  }
}

// ---------------- scan pass A: per-chunk (A = prod lam, B = local scan) ----------------
__global__ __launch_bounds__(256)
void scan_passA(const unsigned int* __restrict__ pack, float* __restrict__ cA, float* __restrict__ cB){
  const int d0 = (blockIdx.x*256 + threadIdx.x)*2;   // gridDim.x = D/512 = 2
  const int c = blockIdx.y, b = blockIdx.z;
  size_t base = ((size_t)b*SEQ + (size_t)c*CL)*D_MODEL + d0;
  float A0=1.f, A1=1.f, s0=0.f, s1=0.f;
  #pragma unroll 8
  for (int t=0;t<CL;t++){
    uint2 p = *(const uint2*)(pack + base + (size_t)t*D_MODEL);
    float om0 = bf2f(p.x & 0xffffu), dr0 = bf2f(p.x >> 16);
    float om1 = bf2f(p.y & 0xffffu), dr1 = bf2f(p.y >> 16);
    float l0 = 1.f - om0, l1 = 1.f - om1;
    A0 *= l0; A1 *= l1;
    s0 = fmaf(l0, s0, dr0);
    s1 = fmaf(l1, s1, dr1);
  }
  const size_t ci = ((size_t)b*NC + c)*D_MODEL + d0;
  *(float2*)(cA+ci) = make_float2(A0,A1);
  *(float2*)(cB+ci) = make_float2(s0,s1);
}

// ---------------- scan pass B: sequential chunk combine + final_state ----------------
__global__ __launch_bounds__(256)
void scan_passB(const float* __restrict__ cA, const float* __restrict__ cB,
                float* __restrict__ cS, float* __restrict__ fstate){
  const int d0 = (blockIdx.x*256 + threadIdx.x)*2;  // gridDim.x = 2
  const int b = blockIdx.y;
  float s0=0.f, s1=0.f;
  for (int c=0;c<NC;c++){
    const size_t ci = ((size_t)b*NC + c)*D_MODEL + d0;
    *(float2*)(cS+ci) = make_float2(s0,s1);
    float2 a  = *(const float2*)(cA+ci);
    float2 bb = *(const float2*)(cB+ci);
    s0 = fmaf(a.x, s0, bb.x);
    s1 = fmaf(a.y, s1, bb.y);
  }
  *(float2*)(fstate + (size_t)b*D_MODEL + d0) = make_float2(s0,s1);
}

// ---------------- scan pass C: re-scan chunks, emit states (bf16) ----------------
__global__ __launch_bounds__(256)
void scan_passC(const unsigned int* __restrict__ pack, const float* __restrict__ cS,
                unsigned short* __restrict__ statesb){
  const int d0 = (blockIdx.x*256 + threadIdx.x)*2;
  const int c = blockIdx.y, b = blockIdx.z;
  float2 sv = *(const float2*)(cS + ((size_t)b*NC + c)*D_MODEL + d0);
  float s0 = sv.x, s1 = sv.y;
  size_t base = ((size_t)b*SEQ + (size_t)c*CL)*D_MODEL + d0;
  #pragma unroll 8
  for (int t=0;t<CL;t++){
    uint2 p = *(const uint2*)(pack + base + (size_t)t*D_MODEL);
    float om0 = bf2f(p.x & 0xffffu), dr0 = bf2f(p.x >> 16);
    float om1 = bf2f(p.y & 0xffffu), dr1 = bf2f(p.y >> 16);
    s0 = fmaf(-om0, s0, s0) + dr0;   // s = (1-om)*s + dr, decay-precise
    s1 = fmaf(-om1, s1, s1) + dr1;
    unsigned int w = ((unsigned int)f2bf(s1) << 16) | (unsigned int)f2bf(s0);
    *(unsigned int*)(statesb + base + (size_t)t*D_MODEL) = w;
  }
}

// ---------------- GEMM out: y = states @ W_out^T + states + b_out ----------------
__global__ __launch_bounds__(256, 2)
void gemm_out_kernel(const unsigned short* __restrict__ Sb,
                     const unsigned short* __restrict__ Wob,
                     const float* __restrict__ b_out,
                     float* __restrict__ y)
{
  __shared__ unsigned short sA[128*64];
  __shared__ unsigned short sB[128*64];
  const int tid  = threadIdx.x;
  const int lane = tid & 63;
  const int wave = tid >> 6;
  const int wr = wave >> 1, wc = wave & 1;
  const int brow = blockIdx.y * 128;
  const int bcol = blockIdx.x * 128;

  const f32x4 zero = {0.f,0.f,0.f,0.f};
  f32x4 acc[4][4];
  #pragma unroll
  for (int a=0;a<4;a++)
    #pragma unroll
    for (int b=0;b<4;b++) acc[a][b]=zero;

  for (int kt = 0; kt < D_MODEL/64; ++kt){
    __syncthreads();
    const size_t kbyte = (size_t)kt*128;
    #pragma unroll
    for (int i=0;i<4;i++){
      const int ob = i*256 + wave*64;
      const int o  = ob + lane;
      const int r  = o >> 3;
      const int cb = (o & 7) * 16;
      gload16((const char*)Sb  + (size_t)(brow + r)*(D_MODEL*2) + kbyte + cb, (char*)sA + (size_t)ob*16);
      gload16((const char*)Wob + (size_t)(bcol + r)*(D_MODEL*2) + kbyte + cb, (char*)sB + (size_t)ob*16);
    }
    __syncthreads();
    #pragma unroll
    for (int ks=0; ks<2; ++ks){
      s16x8 af[4], bf[4];
      #pragma unroll
      for (int mi=0; mi<4; mi++){
        int row = wr*64 + mi*16 + (lane & 15);
        int boff = row*128 + ks*64 + ((lane>>4)*16);
        af[mi] = *(const s16x8*)((const char*)sA + boff);
      }
      #pragma unroll
      for (int ni=0; ni<4; ni++){
        int n = wc*64 + ni*16 + (lane & 15);
        int boff = n*128 + ks*64 + ((lane>>4)*16);
        bf[ni] = *(const s16x8*)((const char*)sB + boff);
      }
      #pragma unroll
      for (int mi=0; mi<4; mi++)
        #pragma unroll
        for (int ni=0; ni<4; ni++)
          acc[mi][ni] = __builtin_amdgcn_mfma_f32_16x16x32_bf16(af[mi], bf[ni], acc[mi][ni], 0,0,0);
    }
  }
  #pragma unroll
  for (int ni=0; ni<4; ni++){
    const int col = bcol + wc*64 + ni*16 + (lane & 15);
    const float vb = b_out[col];
    #pragma unroll
    for (int mi=0; mi<4; mi++){
      #pragma unroll
      for (int q=0; q<4; q++){
        const int row = brow + wr*64 + mi*16 + ((lane>>4)*4) + q;
        const size_t idx = (size_t)row*D_MODEL + col;
        y[idx] = acc[mi][ni][q] + bf2f((unsigned int)Sb[idx]) + vb;
      }
    }
  }
}

// ---------------- LayerNorm ----------------
__global__ __launch_bounds__(256)
void ln_kernel(const float* __restrict__ y, const float* __restrict__ gamma,
               const float* __restrict__ beta, float* __restrict__ out)
{
  const int row = blockIdx.x;
  const int tid = threadIdx.x;
  const float4* yr = (const float4*)(y + (size_t)row*D_MODEL);
  float4 v = yr[tid];
  float s = v.x+v.y+v.z+v.w;
  float q = v.x*v.x + v.y*v.y + v.z*v.z + v.w*v.w;
  #pragma unroll
  for (int off=32; off>0; off>>=1){ s += __shfl_xor(s, off); q += __shfl_xor(q, off); }
  __shared__ float rs[4], rq[4];
  const int wave = tid>>6, lane = tid&63;
  if (lane==0){ rs[wave]=s; rq[wave]=q; }
  __syncthreads();
  float ts = rs[0]+rs[1]+rs[2]+rs[3];
  float tq = rq[0]+rq[1]+rq[2]+rq[3];
  float mu  = ts * (1.f/D_MODEL);
  float var = tq * (1.f/D_MODEL) - mu*mu;
  float inv = rsqrtf(var + 1e-5f);
  float4 g = ((const float4*)gamma)[tid];
  float4 b = ((const float4*)beta)[tid];
  float4 o;
  o.x = (v.x-mu)*inv*g.x + b.x;
  o.y = (v.y-mu)*inv*g.y + b.y;
  o.z = (v.z-mu)*inv*g.z + b.z;
  o.w = (v.w-mu)*inv*g.w + b.w;
  ((float4*)(out + (size_t)row*D_MODEL))[tid] = o;
}

extern "C" void kernel_launch(void* const* d_in, const int* in_sizes, int n_in,
                              void* d_out, int out_size, void* d_ws, size_t ws_size,
                              hipStream_t stream) {
  const float* x         = (const float*)d_in[0];
  const float* delta     = (const float*)d_in[1];
  const float* log_decay = (const float*)d_in[2];
  const float* W_in      = (const float*)d_in[3];
  const float* b_in      = (const float*)d_in[4];
  const float* W_gate    = (const float*)d_in[5];
  const float* b_gate    = (const float*)d_in[6];
  const float* W_out     = (const float*)d_in[7];
  const float* b_out     = (const float*)d_in[8];
  const float* gamma     = (const float*)d_in[9];
  const float* beta      = (const float*)d_in[10];

  char* w = (char*)d_ws;
  unsigned short* xb   = (unsigned short*)(w);                 // 64 MiB, reused as statesb
  unsigned short* Wib  = (unsigned short*)(w + 67108864);      // 2 MiB
  unsigned short* Wgb  = (unsigned short*)(w + 69206016);      // 2 MiB
  unsigned short* Wob  = (unsigned short*)(w + 71303168);      // 2 MiB
  float*          decay= (float*)        (w + 73400320);       // 4 KiB
  float*          cA   = (float*)        (w + 73404416);       // 2 MiB
  float*          cB   = (float*)        (w + 75501568);       // 2 MiB
  float*          cS   = (float*)        (w + 77598720);       // 2 MiB
  unsigned int*   pack = (unsigned int*) (w + 79695872);       // 128 MiB, reused as y
  float*          ybuf = (float*)pack;
  unsigned short* statesb = xb;

  float* out    = (float*)d_out;
  float* fstate = out + (size_t)MROWS*D_MODEL;

  hipLaunchKernelGGL(prep_x_kernel, dim3(8192), dim3(256), 0, stream, x, xb, MROWS*D_MODEL/4);
  hipLaunchKernelGGL(prep_w_kernel, dim3(1024), dim3(256), 0, stream,
                     W_in, W_gate, W_out, log_decay, Wib, Wgb, Wob, decay);
  hipLaunchKernelGGL(gemm_dual_kernel, dim3(8,256), dim3(256), 0, stream,
                     xb, Wib, Wgb, b_in, b_gate, decay, delta, pack);
  hipLaunchKernelGGL(scan_passA, dim3(2,NC,BATCH), dim3(256), 0, stream, pack, cA, cB);
  hipLaunchKernelGGL(scan_passB, dim3(2,BATCH), dim3(256), 0, stream, cA, cB, cS, fstate);
  hipLaunchKernelGGL(scan_passC, dim3(2,NC,BATCH), dim3(256), 0, stream, pack, cS, statesb);
  hipLaunchKernelGGL(gemm_out_kernel, dim3(8,256), dim3(256), 0, stream, statesb, Wob, b_out, ybuf);
  hipLaunchKernelGGL(ln_kernel, dim3(MROWS), dim3(256), 0, stream, ybuf, gamma, beta, out);
}

// Round 2
// 425.030 us; speedup vs baseline: 1.1123x; 1.1123x over previous
//
#include <hip/hip_runtime.h>
#include <hip/hip_bf16.h>

#define D_MODEL 1024
#define BATCH 8
#define SEQ 4096
#define MROWS (BATCH*SEQ)   // 32768
#define NC 64               // number of scan chunks
#define CL 64               // chunk length (NC*CL == SEQ)

typedef __attribute__((ext_vector_type(4))) float f32x4;
typedef __attribute__((ext_vector_type(8))) short s16x8;

__device__ __forceinline__ unsigned short f2bf(float f){
  union { float f; unsigned int u; } v; v.f = f;
  return (unsigned short)((v.u + 0x7fffu + ((v.u >> 16) & 1u)) >> 16);
}
__device__ __forceinline__ float bf2f(unsigned int bits){
  union { unsigned int u; float f; } v; v.u = bits << 16; return v.f;
}

__device__ __forceinline__ void gload16(const void* g, void* l){
  __builtin_amdgcn_global_load_lds(
      (const __attribute__((address_space(1))) unsigned int*)g,
      (__attribute__((address_space(3))) unsigned int*)l, 16, 0, 0);
}

// ---------------- prep: x -> bf16 ----------------
__global__ __launch_bounds__(256)
void prep_x_kernel(const float* __restrict__ x, unsigned short* __restrict__ xb, int n4){
  int i = blockIdx.x*256 + threadIdx.x;
  int stride = gridDim.x*256;
  for (; i < n4; i += stride){
    float4 v = ((const float4*)x)[i];
    ushort4 o;
    o.x = f2bf(v.x); o.y = f2bf(v.y); o.z = f2bf(v.z); o.w = f2bf(v.w);
    ((ushort4*)xb)[i] = o;
  }
}

// ---------------- prep: weights -> bf16, decay ----------------
__global__ __launch_bounds__(256)
void prep_w_kernel(const float* __restrict__ Wi, const float* __restrict__ Wg,
                   const float* __restrict__ Wo, const float* __restrict__ ld,
                   unsigned short* __restrict__ Wib, unsigned short* __restrict__ Wgb,
                   unsigned short* __restrict__ Wob, float* __restrict__ decay){
  int i = blockIdx.x*256 + threadIdx.x;   // grid covers D*D/4 exactly
  {
    float4 a = ((const float4*)Wi)[i]; ushort4 o;
    o.x=f2bf(a.x); o.y=f2bf(a.y); o.z=f2bf(a.z); o.w=f2bf(a.w); ((ushort4*)Wib)[i]=o;
    a = ((const float4*)Wg)[i];
    o.x=f2bf(a.x); o.y=f2bf(a.y); o.z=f2bf(a.z); o.w=f2bf(a.w); ((ushort4*)Wgb)[i]=o;
    a = ((const float4*)Wo)[i];
    o.x=f2bf(a.x); o.y=f2bf(a.y); o.z=f2bf(a.z); o.w=f2bf(a.w); ((ushort4*)Wob)[i]=o;
  }
  if (i < D_MODEL){
    float v = ld[i];
    float sp = fmaxf(v, 0.f) + log1pf(expf(-fabsf(v)));   // stable softplus
    decay[i] = sp + 1e-4f;
  }
}

// ---------------- dual GEMM: update & gate, fused lambda/drive epilogue ----------------
// C[m][e] = sum_d X[m][d] * W[e][d]  (B^T layout: W rows are output cols)
// LDS: linear dest for global_load_lds; XOR-swizzled CONTENT via pre-swizzled
// global source chunk; same XOR applied on ds_read (T2, both-sides rule).
__global__ __launch_bounds__(256, 2)
void gemm_dual_kernel(const unsigned short* __restrict__ Xb,
                      const unsigned short* __restrict__ Wib,
                      const unsigned short* __restrict__ Wgb,
                      const float* __restrict__ b_in,
                      const float* __restrict__ b_gate,
                      const float* __restrict__ decay,
                      const float* __restrict__ delta,
                      unsigned int* __restrict__ pack)
{
  __shared__ unsigned short sA[128*64];
  __shared__ unsigned short sBi[128*64];
  __shared__ unsigned short sBg[128*64];
  const int tid  = threadIdx.x;
  const int lane = tid & 63;
  const int wave = tid >> 6;
  const int wr = wave >> 1, wc = wave & 1;
  // XCD-chunked bijective swizzle: 2048 blocks, 8 XCDs, 256 blocks/XCD.
  const int bid = blockIdx.x;
  const int swz = ((bid & 7) << 8) | (bid >> 3);
  const int bcol = (swz & 7) * 128;
  const int brow = (swz >> 3) * 128;

  const f32x4 zero = {0.f,0.f,0.f,0.f};
  f32x4 accU[4][4], accG[4][4];
  #pragma unroll
  for (int a=0;a<4;a++)
    #pragma unroll
    for (int b=0;b<4;b++){ accU[a][b]=zero; accG[a][b]=zero; }

  for (int kt = 0; kt < D_MODEL/64; ++kt){
    __syncthreads();
    const size_t kbyte = (size_t)kt*128;   // 64 bf16 = 128 bytes
    #pragma unroll
    for (int i=0;i<4;i++){
      const int ob = i*256 + wave*64;          // wave-uniform 16B-unit base
      const int o  = ob + lane;
      const int r  = o >> 3;                   // 8 x 16B per 128B row
      const int cb = ((o & 7) ^ (r & 7)) * 16; // pre-swizzled source chunk
      gload16((const char*)Xb  + (size_t)(brow + r)*(D_MODEL*2) + kbyte + cb, (char*)sA  + (size_t)ob*16);
      gload16((const char*)Wib + (size_t)(bcol + r)*(D_MODEL*2) + kbyte + cb, (char*)sBi + (size_t)ob*16);
      gload16((const char*)Wgb + (size_t)(bcol + r)*(D_MODEL*2) + kbyte + cb, (char*)sBg + (size_t)ob*16);
    }
    __syncthreads();   // compiler drains vmcnt before s_barrier
    #pragma unroll
    for (int ks=0; ks<2; ++ks){
      s16x8 af[4], bi[4], bg[4];
      #pragma unroll
      for (int mi=0; mi<4; mi++){
        int row = wr*64 + mi*16 + (lane & 15);
        int chunk = (ks*4 + (lane>>4)) ^ (row & 7);
        af[mi] = *(const s16x8*)((const char*)sA + row*128 + chunk*16);
      }
      #pragma unroll
      for (int ni=0; ni<4; ni++){
        int n = wc*64 + ni*16 + (lane & 15);
        int chunk = (ks*4 + (lane>>4)) ^ (n & 7);
        bi[ni] = *(const s16x8*)((const char*)sBi + n*128 + chunk*16);
        bg[ni] = *(const s16x8*)((const char*)sBg + n*128 + chunk*16);
      }
      #pragma unroll
      for (int mi=0; mi<4; mi++)
        #pragma unroll
        for (int ni=0; ni<4; ni++){
          accU[mi][ni] = __builtin_amdgcn_mfma_f32_16x16x32_bf16(af[mi], bi[ni], accU[mi][ni], 0,0,0);
          accG[mi][ni] = __builtin_amdgcn_mfma_f32_16x16x32_bf16(af[mi], bg[ni], accG[mi][ni], 0,0,0);
        }
    }
  }
  // epilogue: u,g -> lambda/drive, packed bf16x2 {drive(hi), 1-lambda(lo)}
  #pragma unroll
  for (int ni=0; ni<4; ni++){
    const int col = bcol + wc*64 + ni*16 + (lane & 15);
    const float vb = b_in[col], vg = b_gate[col], dc = decay[col];
    #pragma unroll
    for (int mi=0; mi<4; mi++){
      #pragma unroll
      for (int q=0; q<4; q++){
        const int row = brow + wr*64 + mi*16 + ((lane>>4)*4) + q;
        const size_t idx = (size_t)row*D_MODEL + col;
        float u = accU[mi][ni][q] + vb;
        float z = accG[mi][ni][q] + vg;
        float g = 1.f/(1.f + __expf(-z));
        float dt = fmaxf(delta[idx], 1e-4f);
        float lam = __expf(-dc*dt);
        float omla = 1.f - lam;
        float drv = omla * g * u;
        pack[idx] = ((unsigned int)f2bf(drv) << 16) | (unsigned int)f2bf(omla);
      }
    }
  }
}

// ---------------- scan pass A: per-chunk (A = prod lam, B = local scan) ----------------
__global__ __launch_bounds__(256)
void scan_passA(const unsigned int* __restrict__ pack, float* __restrict__ cA, float* __restrict__ cB){
  const int d0 = (blockIdx.x*256 + threadIdx.x)*2;   // gridDim.x = D/512 = 2
  const int c = blockIdx.y, b = blockIdx.z;
  size_t base = ((size_t)b*SEQ + (size_t)c*CL)*D_MODEL + d0;
  float A0=1.f, A1=1.f, s0=0.f, s1=0.f;
  #pragma unroll 8
  for (int t=0;t<CL;t++){
    uint2 p = *(const uint2*)(pack + base + (size_t)t*D_MODEL);
    float om0 = bf2f(p.x & 0xffffu), dr0 = bf2f(p.x >> 16);
    float om1 = bf2f(p.y & 0xffffu), dr1 = bf2f(p.y >> 16);
    float l0 = 1.f - om0, l1 = 1.f - om1;
    A0 *= l0; A1 *= l1;
    s0 = fmaf(l0, s0, dr0);
    s1 = fmaf(l1, s1, dr1);
  }
  const size_t ci = ((size_t)b*NC + c)*D_MODEL + d0;
  *(float2*)(cA+ci) = make_float2(A0,A1);
  *(float2*)(cB+ci) = make_float2(s0,s1);
}

// ---------------- scan pass B: sequential chunk combine + final_state ----------------
__global__ __launch_bounds__(256)
void scan_passB(const float* __restrict__ cA, const float* __restrict__ cB,
                float* __restrict__ cS, float* __restrict__ fstate){
  const int d0 = (blockIdx.x*256 + threadIdx.x)*2;  // gridDim.x = 2
  const int b = blockIdx.y;
  float s0=0.f, s1=0.f;
  for (int c=0;c<NC;c++){
    const size_t ci = ((size_t)b*NC + c)*D_MODEL + d0;
    *(float2*)(cS+ci) = make_float2(s0,s1);
    float2 a  = *(const float2*)(cA+ci);
    float2 bb = *(const float2*)(cB+ci);
    s0 = fmaf(a.x, s0, bb.x);
    s1 = fmaf(a.y, s1, bb.y);
  }
  *(float2*)(fstate + (size_t)b*D_MODEL + d0) = make_float2(s0,s1);
}

// ---------------- scan pass C: re-scan chunks, emit states (bf16) ----------------
__global__ __launch_bounds__(256)
void scan_passC(const unsigned int* __restrict__ pack, const float* __restrict__ cS,
                unsigned short* __restrict__ statesb){
  const int d0 = (blockIdx.x*256 + threadIdx.x)*2;
  const int c = blockIdx.y, b = blockIdx.z;
  float2 sv = *(const float2*)(cS + ((size_t)b*NC + c)*D_MODEL + d0);
  float s0 = sv.x, s1 = sv.y;
  size_t base = ((size_t)b*SEQ + (size_t)c*CL)*D_MODEL + d0;
  #pragma unroll 8
  for (int t=0;t<CL;t++){
    uint2 p = *(const uint2*)(pack + base + (size_t)t*D_MODEL);
    float om0 = bf2f(p.x & 0xffffu), dr0 = bf2f(p.x >> 16);
    float om1 = bf2f(p.y & 0xffffu), dr1 = bf2f(p.y >> 16);
    s0 = fmaf(-om0, s0, s0) + dr0;   // s = (1-om)*s + dr, decay-precise
    s1 = fmaf(-om1, s1, s1) + dr1;
    unsigned int w = ((unsigned int)f2bf(s1) << 16) | (unsigned int)f2bf(s0);
    *(unsigned int*)(statesb + base + (size_t)t*D_MODEL) = w;
  }
}

// ---------------- GEMM out: y = states @ W_out^T + b_out (states added in LN) --------
__global__ __launch_bounds__(256, 3)
void gemm_out_kernel(const unsigned short* __restrict__ Sb,
                     const unsigned short* __restrict__ Wob,
                     const float* __restrict__ b_out,
                     float* __restrict__ y)
{
  __shared__ unsigned short sA[128*64];
  __shared__ unsigned short sB[128*64];
  const int tid  = threadIdx.x;
  const int lane = tid & 63;
  const int wave = tid >> 6;
  const int wr = wave >> 1, wc = wave & 1;
  const int bid = blockIdx.x;
  const int swz = ((bid & 7) << 8) | (bid >> 3);
  const int bcol = (swz & 7) * 128;
  const int brow = (swz >> 3) * 128;

  const f32x4 zero = {0.f,0.f,0.f,0.f};
  f32x4 acc[4][4];
  #pragma unroll
  for (int a=0;a<4;a++)
    #pragma unroll
    for (int b=0;b<4;b++) acc[a][b]=zero;

  for (int kt = 0; kt < D_MODEL/64; ++kt){
    __syncthreads();
    const size_t kbyte = (size_t)kt*128;
    #pragma unroll
    for (int i=0;i<4;i++){
      const int ob = i*256 + wave*64;
      const int o  = ob + lane;
      const int r  = o >> 3;
      const int cb = ((o & 7) ^ (r & 7)) * 16;
      gload16((const char*)Sb  + (size_t)(brow + r)*(D_MODEL*2) + kbyte + cb, (char*)sA + (size_t)ob*16);
      gload16((const char*)Wob + (size_t)(bcol + r)*(D_MODEL*2) + kbyte + cb, (char*)sB + (size_t)ob*16);
    }
    __syncthreads();
    #pragma unroll
    for (int ks=0; ks<2; ++ks){
      s16x8 af[4], bf[4];
      #pragma unroll
      for (int mi=0; mi<4; mi++){
        int row = wr*64 + mi*16 + (lane & 15);
        int chunk = (ks*4 + (lane>>4)) ^ (row & 7);
        af[mi] = *(const s16x8*)((const char*)sA + row*128 + chunk*16);
      }
      #pragma unroll
      for (int ni=0; ni<4; ni++){
        int n = wc*64 + ni*16 + (lane & 15);
        int chunk = (ks*4 + (lane>>4)) ^ (n & 7);
        bf[ni] = *(const s16x8*)((const char*)sB + n*128 + chunk*16);
      }
      #pragma unroll
      for (int mi=0; mi<4; mi++)
        #pragma unroll
        for (int ni=0; ni<4; ni++)
          acc[mi][ni] = __builtin_amdgcn_mfma_f32_16x16x32_bf16(af[mi], bf[ni], acc[mi][ni], 0,0,0);
    }
  }
  #pragma unroll
  for (int ni=0; ni<4; ni++){
    const int col = bcol + wc*64 + ni*16 + (lane & 15);
    const float vb = b_out[col];
    #pragma unroll
    for (int mi=0; mi<4; mi++){
      #pragma unroll
      for (int q=0; q<4; q++){
        const int row = brow + wr*64 + mi*16 + ((lane>>4)*4) + q;
        const size_t idx = (size_t)row*D_MODEL + col;
        y[idx] = acc[mi][ni][q] + vb;
      }
    }
  }
}

// ---------------- LayerNorm (adds residual states here, coalesced) ----------------
__global__ __launch_bounds__(256)
void ln_kernel(const float* __restrict__ y, const unsigned short* __restrict__ statesb,
               const float* __restrict__ gamma, const float* __restrict__ beta,
               float* __restrict__ out)
{
  const int row = blockIdx.x;
  const int tid = threadIdx.x;
  float4 v = ((const float4*)(y + (size_t)row*D_MODEL))[tid];
  ushort4 sb = ((const ushort4*)(statesb + (size_t)row*D_MODEL))[tid];
  v.x += bf2f(sb.x); v.y += bf2f(sb.y); v.z += bf2f(sb.z); v.w += bf2f(sb.w);
  float s = v.x+v.y+v.z+v.w;
  float q = v.x*v.x + v.y*v.y + v.z*v.z + v.w*v.w;
  #pragma unroll
  for (int off=32; off>0; off>>=1){ s += __shfl_xor(s, off); q += __shfl_xor(q, off); }
  __shared__ float rs[4], rq[4];
  const int wave = tid>>6, lane = tid&63;
  if (lane==0){ rs[wave]=s; rq[wave]=q; }
  __syncthreads();
  float ts = rs[0]+rs[1]+rs[2]+rs[3];
  float tq = rq[0]+rq[1]+rq[2]+rq[3];
  float mu  = ts * (1.f/D_MODEL);
  float var = tq * (1.f/D_MODEL) - mu*mu;
  float inv = rsqrtf(var + 1e-5f);
  float4 g = ((const float4*)gamma)[tid];
  float4 b = ((const float4*)beta)[tid];
  float4 o;
  o.x = (v.x-mu)*inv*g.x + b.x;
  o.y = (v.y-mu)*inv*g.y + b.y;
  o.z = (v.z-mu)*inv*g.z + b.z;
  o.w = (v.w-mu)*inv*g.w + b.w;
  ((float4*)(out + (size_t)row*D_MODEL))[tid] = o;
}

extern "C" void kernel_launch(void* const* d_in, const int* in_sizes, int n_in,
                              void* d_out, int out_size, void* d_ws, size_t ws_size,
                              hipStream_t stream) {
  const float* x         = (const float*)d_in[0];
  const float* delta     = (const float*)d_in[1];
  const float* log_decay = (const float*)d_in[2];
  const float* W_in      = (const float*)d_in[3];
  const float* b_in      = (const float*)d_in[4];
  const float* W_gate    = (const float*)d_in[5];
  const float* b_gate    = (const float*)d_in[6];
  const float* W_out     = (const float*)d_in[7];
  const float* b_out     = (const float*)d_in[8];
  const float* gamma     = (const float*)d_in[9];
  const float* beta      = (const float*)d_in[10];

  char* w = (char*)d_ws;
  unsigned short* xb   = (unsigned short*)(w);                 // 64 MiB, reused as statesb
  unsigned short* Wib  = (unsigned short*)(w + 67108864);      // 2 MiB
  unsigned short* Wgb  = (unsigned short*)(w + 69206016);      // 2 MiB
  unsigned short* Wob  = (unsigned short*)(w + 71303168);      // 2 MiB
  float*          decay= (float*)        (w + 73400320);       // 4 KiB
  float*          cA   = (float*)        (w + 73404416);       // 2 MiB
  float*          cB   = (float*)        (w + 75501568);       // 2 MiB
  float*          cS   = (float*)        (w + 77598720);       // 2 MiB
  unsigned int*   pack = (unsigned int*) (w + 79695872);       // 128 MiB, reused as y
  float*          ybuf = (float*)pack;
  unsigned short* statesb = xb;

  float* out    = (float*)d_out;
  float* fstate = out + (size_t)MROWS*D_MODEL;

  hipLaunchKernelGGL(prep_x_kernel, dim3(8192), dim3(256), 0, stream, x, xb, MROWS*D_MODEL/4);
  hipLaunchKernelGGL(prep_w_kernel, dim3(1024), dim3(256), 0, stream,
                     W_in, W_gate, W_out, log_decay, Wib, Wgb, Wob, decay);
  hipLaunchKernelGGL(gemm_dual_kernel, dim3(2048), dim3(256), 0, stream,
                     xb, Wib, Wgb, b_in, b_gate, decay, delta, pack);
  hipLaunchKernelGGL(scan_passA, dim3(2,NC,BATCH), dim3(256), 0, stream, pack, cA, cB);
  hipLaunchKernelGGL(scan_passB, dim3(2,BATCH), dim3(256), 0, stream, cA, cB, cS, fstate);
  hipLaunchKernelGGL(scan_passC, dim3(2,NC,BATCH), dim3(256), 0, stream, pack, cS, statesb);
  hipLaunchKernelGGL(gemm_out_kernel, dim3(2048), dim3(256), 0, stream, statesb, Wob, b_out, ybuf);
  hipLaunchKernelGGL(ln_kernel, dim3(MROWS), dim3(256), 0, stream, ybuf, statesb, gamma, beta, out);
}